// Round 1
// baseline (147.098 us; speedup 1.0000x reference)
//
#include <hip/hip_runtime.h>

#define NB 2000000
static constexpr float EPSF = 1e-4f;

__global__ __launch_bounds__(256) void gcnl_kernel(
    const float* __restrict__ pred_r,
    const float* __restrict__ pred_params,
    const float* __restrict__ pred_corr,
    const float* __restrict__ y_true,
    float* __restrict__ out)
{
    constexpr int G = NB / 4;  // 4 rows per thread -> all-float4 loads
    const int g = blockIdx.x * blockDim.x + threadIdx.x;
    float acc = 0.0f;

    if (g < G) {
        const float4* prv = (const float4*)pred_r;       // 8 floats / 4 rows
        const float4* ppv = (const float4*)pred_params;  // 24 floats / 4 rows
        const float4* pcv = (const float4*)pred_corr;    // 12 floats / 4 rows
        const float4* ytv = (const float4*)y_true;       // 16 floats / 4 rows

        float R[8], P[24], C[12], Y[16];
        float4 t;
        t = prv[2*g+0]; R[0]=t.x; R[1]=t.y; R[2]=t.z; R[3]=t.w;
        t = prv[2*g+1]; R[4]=t.x; R[5]=t.y; R[6]=t.z; R[7]=t.w;
        #pragma unroll
        for (int k = 0; k < 6; ++k) { t = ppv[6*g+k]; P[4*k]=t.x; P[4*k+1]=t.y; P[4*k+2]=t.z; P[4*k+3]=t.w; }
        #pragma unroll
        for (int k = 0; k < 3; ++k) { t = pcv[3*g+k]; C[4*k]=t.x; C[4*k+1]=t.y; C[4*k+2]=t.z; C[4*k+3]=t.w; }
        #pragma unroll
        for (int k = 0; k < 4; ++k) { t = ytv[4*g+k]; Y[4*k]=t.x; Y[4*k+1]=t.y; Y[4*k+2]=t.z; Y[4*k+3]=t.w; }

        #pragma unroll
        for (int j = 0; j < 4; ++j) {
            const float r0 = R[2*j], r1 = R[2*j+1];
            const float pp0 = P[6*j+0], pp1 = P[6*j+1], pp2 = P[6*j+2];
            const float pp3 = P[6*j+3], pp4 = P[6*j+4], pp5 = P[6*j+5];
            const float r12 = C[3*j+0], r13 = C[3*j+1], r23 = C[3*j+2];
            const float revert = Y[4*j+0], Rtop = Y[4*j+1], Top = Y[4*j+2], Close = Y[4*j+3];

            // means and inverse sigmas: s=exp(pp) => 1/s = exp(-pp), log(s^2)/2 = pp
            const float rtop  = __expf(pp0), is_rtop  = __expf(-pp1);
            const float top   = __expf(pp2), is_top   = __expf(-pp3);
            const float close = __expf(pp4), is_close = __expf(-pp5);

            const float d1 = (rtop  - Rtop ) * is_rtop;
            const float d2 = (top   - Top  ) * is_top;
            const float d3 = (close - Close) * is_close;

            // z = clip((x-u)/s, -3, 3): ndtr/erfinv round-trip collapses (eps-clip outside +-3)
            const float z1 = fminf(fmaxf(-d1, -3.0f), 3.0f);
            const float z2 = fminf(fmaxf(-d2, -3.0f), 3.0f);
            const float z3 = fminf(fmaxf(-d3, -3.0f), 3.0f);

            const float detR = 1.0f + 2.0f*r12*r13*r23 - r12*r12 - r13*r13 - r23*r23;
            const float inv_det = 1.0f / detR;
            const float i00 = (1.0f - r23*r23) * inv_det;
            const float i01 = (r13*r23 - r12) * inv_det;
            const float i02 = (r12*r23 - r13) * inv_det;
            const float i11 = (1.0f - r13*r13) * inv_det;
            const float i12 = (r12*r13 - r23) * inv_det;
            const float i22 = (1.0f - r12*r12) * inv_det;

            const float exp_term = 0.5f*((i00-1.0f)*z1*z1 + (i11-1.0f)*z2*z2 + (i22-1.0f)*z3*z3)
                                 + (i01*z1*z2 + i02*z1*z3 + i12*z2*z3);
            const float c_gauss = 0.5f*__logf(fmaxf(detR, EPSF)) + exp_term;
            // nll sum: 0.5*d^2 + log(s) with log(s)=pp
            const float nll = 0.5f*(d1*d1 + d2*d2 + d3*d3) + (pp1 + pp3 + pp5);
            const float copula = revert * (c_gauss + nll);

            // cross-entropy term: -logp[sel] = lse - r_sel
            const float m   = fmaxf(r0, r1);
            const float lse = m + __logf(1.0f + __expf(-fabsf(r0 - r1)));
            const float rsel = (revert != 0.0f) ? r1 : r0;

            acc += copula + (lse - rsel);
        }
    }

    // wave (64) shuffle reduce
    #pragma unroll
    for (int off = 32; off > 0; off >>= 1) acc += __shfl_down(acc, off, 64);

    __shared__ float warp_sums[4];
    const int lane = threadIdx.x & 63;
    const int wid  = threadIdx.x >> 6;
    if (lane == 0) warp_sums[wid] = acc;
    __syncthreads();
    if (threadIdx.x == 0) {
        const float s = warp_sums[0] + warp_sums[1] + warp_sums[2] + warp_sums[3];
        atomicAdd(out, s * (1.0f / (float)NB));
    }
}

extern "C" void kernel_launch(void* const* d_in, const int* in_sizes, int n_in,
                              void* d_out, int out_size, void* d_ws, size_t ws_size,
                              hipStream_t stream) {
    const float* pred_r      = (const float*)d_in[0];
    const float* pred_params = (const float*)d_in[1];
    const float* pred_corr   = (const float*)d_in[2];
    const float* y_true      = (const float*)d_in[3];
    float* out = (float*)d_out;

    // output is poisoned (0xAA) before every timed replay -> zero it in-graph
    hipMemsetAsync(out, 0, sizeof(float), stream);

    constexpr int G = NB / 4;
    const int block = 256;
    const int grid = (G + block - 1) / block;  // 1954
    hipLaunchKernelGGL(gcnl_kernel, dim3(grid), dim3(block), 0, stream,
                       pred_r, pred_params, pred_corr, y_true, out);
}